// Round 4
// baseline (101.279 us; speedup 1.0000x reference)
//
#include <hip/hip_runtime.h>

#define HH 128
#define WW 128

typedef __bf16 bf16x8 __attribute__((ext_vector_type(8)));
typedef float f32x4 __attribute__((ext_vector_type(4)));

static __device__ __forceinline__ unsigned short f2bf(float f) {
  unsigned int u = __float_as_uint(f);
  u = (u + 0x7FFFu + ((u >> 16) & 1u)) >> 16;  // RNE
  return (unsigned short)u;
}

// ---------------------------------------------------------------------------
// Prep 1: pack conv_w [co][ci][tap] into MFMA A-fragment order (bf16):
//   wfrag[f = h*9+tap][cotile][lane][i] = conv_w[cotile*16 + lane%16]
//                                               [h*32 + (lane/16)*8 + i][tap]
// ---------------------------------------------------------------------------
__global__ __launch_bounds__(256) void prep_wfrag(const float* __restrict__ conv_w,
                                                  unsigned short* __restrict__ wfrag) {
  int tid = blockIdx.x * 256 + threadIdx.x;
  if (tid >= 18 * 2048) return;
  int i    = tid & 7;
  int lane = (tid >> 3) & 63;
  int cot  = (tid >> 9) & 3;
  int f    = tid >> 11;           // 0..17
  int h    = f / 9;               // ci half
  int tap  = f - h * 9;
  int co   = cot * 16 + (lane & 15);
  int ci   = h * 32 + (lane >> 4) * 8 + i;
  wfrag[tid] = f2bf(conv_w[(co * 64 + ci) * 9 + tap]);
}

// ---------------------------------------------------------------------------
// Prep 2: grouped conv of spatially-constant input -> 9-case boundary table
//   ext[b][co][cy][cx]  (includes conv_b + extra_b)
// ---------------------------------------------------------------------------
__global__ __launch_bounds__(256) void prep_ext(const float* __restrict__ extra_in,
                                                const float* __restrict__ extra_w,
                                                const float* __restrict__ conv_b,
                                                const float* __restrict__ extra_b,
                                                float* __restrict__ ext) {
  int t = blockIdx.x * 256 + threadIdx.x;
  if (t >= 32 * 64) return;
  int b = t >> 6, co = t & 63;
  float base = conv_b[co] + extra_b[co];
  float acc[3][3];
#pragma unroll
  for (int i = 0; i < 3; ++i)
#pragma unroll
    for (int j = 0; j < 3; ++j) acc[i][j] = 0.f;

#pragma unroll
  for (int f = 0; f < 3; ++f) {
    float e = extra_in[b * 192 + co * 3 + f];
    const float* w = extra_w + (co * 3 + f) * 9;
    float rs[3][3];
#pragma unroll
    for (int ky = 0; ky < 3; ++ky) {
      float w0 = w[ky * 3 + 0], w1 = w[ky * 3 + 1], w2 = w[ky * 3 + 2];
      rs[ky][0] = w1 + w2;
      rs[ky][1] = w0 + w1 + w2;
      rs[ky][2] = w0 + w1;
    }
#pragma unroll
    for (int cx = 0; cx < 3; ++cx) {
      acc[0][cx] += e * (rs[1][cx] + rs[2][cx]);
      acc[1][cx] += e * (rs[0][cx] + rs[1][cx] + rs[2][cx]);
      acc[2][cx] += e * (rs[0][cx] + rs[1][cx]);
    }
  }
#pragma unroll
  for (int cy = 0; cy < 3; ++cy)
#pragma unroll
    for (int cx = 0; cx < 3; ++cx)
      ext[t * 9 + cy * 3 + cx] = base + acc[cy][cx];
}

// ---------------------------------------------------------------------------
// Main: implicit-GEMM conv via mfma_f32_16x16x32_bf16, software-pipelined.
// Block = (batch, 4 rows x 64 cols), 4 waves, wave = 1 output row.
// ci halves double-buffered in LDS (2 x 25.5 KB): phase A computes half 0
// while its tap loop stages half 1 item-by-item (no inner barriers -> waves
// desync, staging latency hides under other waves' MFMA). Tap loops fully
// unrolled so the compiler pipelines wfrag/LDS fragment loads across taps.
// ---------------------------------------------------------------------------
__global__ __launch_bounds__(256, 3) void conv_mfma(const float* __restrict__ x,
                                                    const unsigned short* __restrict__ wfrag,
                                                    const float* __restrict__ ext,
                                                    float* __restrict__ out) {
  const int b  = blockIdx.z;
  const int y0 = blockIdx.y * 4;
  const int x0 = blockIdx.x * 64;
  const int tid  = threadIdx.x;
  const int lane = tid & 63;
  const int wv   = tid >> 6;  // wave id = output row offset

  __shared__ __align__(16) unsigned char sbuf[2][6 * 68 * 64];  // per half: [r][c][32ci]

  const float* xb = x + (size_t)b * 64 * HH * WW;

  f32x4 acc[4][4];
#pragma unroll
  for (int i = 0; i < 4; ++i)
#pragma unroll
    for (int j = 0; j < 4; ++j) acc[i][j] = (f32x4){0.f, 0.f, 0.f, 0.f};

  const int pix = lane & 15;
  const int g   = lane >> 4;

  // stage one item (8 ci of one (r,c)) of half h into buffer buf
  auto stage_item = [&](int buf, int h, int q) {
    if (q < 1584) {
      int c   = q % 66;
      int t2  = q / 66;
      int cig = t2 & 3;
      int r   = t2 >> 2;
      int y_in = y0 - 1 + r;
      int x_in = x0 - 1 + c;
      bool inb = ((unsigned)y_in < 128u) & ((unsigned)x_in < 128u);
      const float* src = xb + (size_t)(h * 32 + cig * 8) * (HH * WW) + y_in * WW + x_in;
      unsigned int pk[4] = {0u, 0u, 0u, 0u};
      if (inb) {
#pragma unroll
        for (int j = 0; j < 8; ++j) {
          unsigned short us = f2bf(src[j * (HH * WW)]);
          pk[j >> 1] |= ((unsigned int)us) << ((j & 1) * 16);
        }
      }
      int byte = (r * 68 + c) * 64 + cig * 16;
      byte ^= ((c ^ (c >> 2)) & 3) << 4;
      *(uint4*)(sbuf[buf] + byte) = make_uint4(pk[0], pk[1], pk[2], pk[3]);
    }
  };

  auto compute_tap = [&](int buf, int h, int tap) {
    const int ky = tap / 3, kx = tap - ky * 3;
    const unsigned short* wbase = wfrag + (size_t)(h * 9 + tap) * 2048 + lane * 8;
    bf16x8 af[4];
#pragma unroll
    for (int cot = 0; cot < 4; ++cot)
      af[cot] = *(const bf16x8*)(wbase + cot * 512);
    bf16x8 pf[4];
    const int r = wv + ky;
#pragma unroll
    for (int m = 0; m < 4; ++m) {
      int c = m * 16 + pix + kx;
      int byte = (r * 68 + c) * 64 + g * 16;
      byte ^= ((c ^ (c >> 2)) & 3) << 4;
      pf[m] = *(const bf16x8*)(sbuf[buf] + byte);
    }
#pragma unroll
    for (int cot = 0; cot < 4; ++cot)
#pragma unroll
      for (int m = 0; m < 4; ++m)
        acc[cot][m] = __builtin_amdgcn_mfma_f32_16x16x32_bf16(af[cot], pf[m],
                                                              acc[cot][m], 0, 0, 0);
  };

  // ---- prologue: stage half 0 completely ----
#pragma unroll
  for (int it = 0; it < 7; ++it) stage_item(0, 0, tid + it * 256);
  __syncthreads();

  // ---- phase A: compute half 0, stage half 1 interleaved per tap ----
#pragma unroll
  for (int tap = 0; tap < 9; ++tap) {
    if (tap < 7) stage_item(1, 1, tid + tap * 256);
    compute_tap(0, 0, tap);
  }
  __syncthreads();

  // ---- phase B: compute half 1 ----
#pragma unroll
  for (int tap = 0; tap < 9; ++tap) compute_tap(1, 1, tap);

  // ---- epilogue: add boundary-case table, coalesced stores ----
  const int y  = y0 + wv;
  const int cy = (y == 0) ? 0 : ((y == HH - 1) ? 2 : 1);
  const float* extb = ext + (size_t)b * 64 * 9;
#pragma unroll
  for (int cot = 0; cot < 4; ++cot) {
#pragma unroll
    for (int m = 0; m < 4; ++m) {
      int xg = x0 + m * 16 + pix;
      int cx = (xg == 0) ? 0 : ((xg == WW - 1) ? 2 : 1);
#pragma unroll
      for (int j = 0; j < 4; ++j) {
        int co = cot * 16 + g * 4 + j;
        float v = acc[cot][m][j] + extb[co * 9 + cy * 3 + cx];
        out[(((size_t)b * 64 + co) * HH + y) * WW + xg] = v;
      }
    }
  }
}

extern "C" void kernel_launch(void* const* d_in, const int* in_sizes, int n_in,
                              void* d_out, int out_size, void* d_ws, size_t ws_size,
                              hipStream_t stream) {
  const float* x        = (const float*)d_in[0];
  const float* extra_in = (const float*)d_in[1];
  const float* conv_w   = (const float*)d_in[2];
  const float* conv_b   = (const float*)d_in[3];
  const float* extra_w  = (const float*)d_in[4];
  const float* extra_b  = (const float*)d_in[5];
  float* out = (float*)d_out;

  unsigned short* wfrag = (unsigned short*)d_ws;              // 73728 B
  float* ext = (float*)((char*)d_ws + 73728);                 // 73728 B

  hipLaunchKernelGGL(prep_wfrag, dim3(144), dim3(256), 0, stream, conv_w, wfrag);
  hipLaunchKernelGGL(prep_ext,   dim3(8),   dim3(256), 0, stream,
                     extra_in, extra_w, conv_b, extra_b, ext);
  hipLaunchKernelGGL(conv_mfma, dim3(2, 32, 32), dim3(256), 0, stream,
                     x, wfrag, ext, out);
}